// Round 18
// baseline (83.315 us; speedup 1.0000x reference)
//
#include <hip/hip_runtime.h>

// BinaryTreeShConv on MI355X (gfx950).
// out[b,v,i] = relu(bias[i] + sum_{p,c,rn} W[i,c,rn] * K[b,v,p,rn] * sig[b, idx[b,v,p], c])
// B=8 V=4096 P=32 C=32 RN=32 OUT=32, CRN=1024.
//
// R17: MEASUREMENT ROUND. Exact R15 kernel (best, 36.5 us) with the body
// repeated 3x (identical work & outputs; idempotent) so the fused dispatch
// exceeds the 75-us harness fills and surfaces in rocprof top-5 with full
// counters. dur_us regresses this round by design; next round reverts.

typedef __attribute__((ext_vector_type(8))) short bf16x8;
typedef __attribute__((ext_vector_type(4))) short short4v;
typedef __attribute__((ext_vector_type(16))) float f32x16;
typedef __attribute__((ext_vector_type(4))) float f32x4;

__device__ __forceinline__ unsigned short f2bf_rne(float f) {
    union { float f; unsigned int u; } x;
    x.f = f;
    unsigned int u = x.u;
    return (unsigned short)((u + 0x7fffu + ((u >> 16) & 1u)) >> 16);
}
__device__ __forceinline__ unsigned short f2bf_rh(float f) {  // round-half-up
    union { float f; unsigned int u; } x;
    x.f = f;
    return (unsigned short)((x.u + 0x8000u) >> 16);
}

// Wf[pair=2s+t][lane][j] = bf16(W[i=16t+(lane&15)][crn=32s+8*(lane>>4)+j])
// plus sig f32 -> bf16 (RNE), 8 elements/thread.
__global__ __launch_bounds__(256) void prep_kernel(
        const float* __restrict__ W, const float* __restrict__ sig,
        unsigned short* __restrict__ Wf, unsigned short* __restrict__ sigbf) {
    int tid = blockIdx.x * 256 + threadIdx.x;
    if (tid < 32768) {
        int j = tid & 7;
        int l = (tid >> 3) & 63;
        int pair = tid >> 9;                    // s*2 + t
        int s = pair >> 1;
        int t = pair & 1;
        int i = 16 * t + (l & 15);
        int crn = 32 * s + 8 * (l >> 4) + j;
        Wf[tid] = f2bf_rne(W[i * 1024 + crn]);
    } else {
        int e = (tid - 32768) * 8;              // sig has 1,048,576 elements
        if (e < 8 * 4096 * 32) {
            f32x4 a = *(const f32x4*)(sig + e);
            f32x4 b = *(const f32x4*)(sig + e + 4);
            bf16x8 v;
            v[0] = (short)f2bf_rne(a[0]); v[1] = (short)f2bf_rne(a[1]);
            v[2] = (short)f2bf_rne(a[2]); v[3] = (short)f2bf_rne(a[3]);
            v[4] = (short)f2bf_rne(b[0]); v[5] = (short)f2bf_rne(b[1]);
            v[6] = (short)f2bf_rne(b[2]); v[7] = (short)f2bf_rne(b[3]);
            *(bf16x8*)(sigbf + e) = v;
        }
    }
}

__global__ __launch_bounds__(512, 8) void fused_kernel(
        const unsigned short* __restrict__ sigbf, const int* __restrict__ pidx,
        const float* __restrict__ ck, const unsigned short* __restrict__ Wf,
        const float* __restrict__ bias, float* __restrict__ out) {
    __shared__ __align__(16) unsigned short ckb[8 * 1024];   // ck tiles, then red
    __shared__ __align__(16) unsigned short T_lds[8 * 1032]; // 16,512 B
    const int tid = threadIdx.x;
    const int l = tid & 63;
    const int g = l >> 5;
    const int cc = l & 31;
    const int wu = __builtin_amdgcn_readfirstlane(tid >> 6);  // wave 0..7 (SGPR)
    const int m0 = blockIdx.x * 8;   // 8 bv per block (same b)
    const int b = m0 >> 12;
    const unsigned short* sgb = sigbf + (size_t)b * (4096 * 32);

    for (int rep = 0; rep < 3; ++rep) {
        // ======== Phase 0: pure streaming; wave wu owns bv wu ========
        int rows[32];
        {
            const int* ip = pidx + (size_t)(m0 + wu) * 32;
            #pragma unroll
            for (int k = 0; k < 32; ++k) rows[k] = ip[k];
        }
        f32x4 st[4];
        {
            const f32x4* ckv = (const f32x4*)(ck + (size_t)(m0 + wu) * 1024);
            #pragma unroll
            for (int i = 0; i < 4; ++i) st[i] = ckv[i * 64 + l];
        }
        unsigned short ga[16];
        #pragma unroll
        for (int h = 0; h < 2; ++h) {
            #pragma unroll
            for (int j = 0; j < 8; ++j) {
                const int rlo = rows[h * 16 + j];
                const int rhi = rows[h * 16 + 8 + j];
                const int row = g ? rhi : rlo;
                ga[h * 8 + j] = sgb[row * 32 + cc];
            }
        }
        // pack ck -> LDS (own region; intra-wave RAW, no barrier needed)
        #pragma unroll
        for (int i = 0; i < 4; ++i) {
            union { f32x4 f; unsigned int u[4]; } x;
            x.f = st[i];
            short4v v = { (short)(x.u[0] >> 16), (short)(x.u[1] >> 16),
                          (short)(x.u[2] >> 16), (short)(x.u[3] >> 16) };
            *(short4v*)(ckb + wu * 1024 + (i * 64 + l) * 4) = v;
        }

        // ======== Phase A ========
        {
            const unsigned short* ct = ckb + wu * 1024;   // [32p][32rn]
            f32x16 acc = {};
            #pragma unroll
            for (int h = 0; h < 2; ++h) {
                bf16x8 af, bfr;
                #pragma unroll
                for (int j = 0; j < 8; ++j) {
                    const int p = h * 16 + 8 * g + j;
                    af[j]  = (short)ga[h * 8 + j];
                    bfr[j] = (short)ct[p * 32 + cc];
                }
                acc = __builtin_amdgcn_mfma_f32_32x32x16_bf16(af, bfr, acc, 0, 0, 0);
            }
            unsigned short* trow = T_lds + wu * 1032 + cc + g * 128;
            #pragma unroll
            for (int r = 0; r < 16; ++r)
                trow[((r & 3) + 8 * (r >> 2)) * 32] = f2bf_rh(acc[r]);
        }
        __syncthreads();   // barrier 1: T ready

        // ======== Phase B: k-split s = 4wu..4wu+3 ========
        f32x4 acc0 = {}, acc1 = {};
        const int lg = l >> 4;
        const int ln = l & 15;
        #pragma unroll
        for (int si = 0; si < 4; ++si) {
            const int s = 4 * wu + si;
            const bf16x8 af =
                *(const bf16x8*)(T_lds + (ln & 7) * 1032 + s * 32 + 8 * lg);
            const bf16x8* wrow = (const bf16x8*)(Wf + (size_t)(s * 2) * 512);
            const bf16x8 b0 = wrow[l];
            const bf16x8 b1 = wrow[64 + l];
            acc0 = __builtin_amdgcn_mfma_f32_16x16x32_bf16(af, b0, acc0, 0, 0, 0);
            acc1 = __builtin_amdgcn_mfma_f32_16x16x32_bf16(af, b1, acc1, 0, 0, 0);
        }

        float* red = (float*)ckb;             // aliases consumed ckb (own region)
        {
            f32x4* rp = (f32x4*)(red + wu * 512);
            rp[l]      = acc0;
            rp[64 + l] = acc1;
        }
        __syncthreads();   // barrier 2: red complete

        if (tid < 256) {
            const int bv  = tid >> 5;
            const int i   = tid & 31;
            const int t   = i >> 4;
            const int col = i & 15;
            const int lgi = bv >> 2;
            const int r   = bv & 3;
            const int li  = lgi * 16 + col;
            const int o   = t * 256 + li * 4 + r;
            float sum = 0.f;
            #pragma unroll
            for (int w2 = 0; w2 < 8; ++w2) sum += red[w2 * 512 + o];
            sum += bias[i];
            out[(size_t)(m0 + bv) * 32 + i] = sum > 0.f ? sum : 0.f;
        }
        __syncthreads();   // barrier 3: epilogue red reads done before next rep
    }
}

extern "C" void kernel_launch(void* const* d_in, const int* in_sizes, int n_in,
                              void* d_out, int out_size, void* d_ws, size_t ws_size,
                              hipStream_t stream) {
    const float* sig  = (const float*)d_in[0];
    const int*   pidx = (const int*)d_in[1];
    const float* ck   = (const float*)d_in[2];
    const float* W    = (const float*)d_in[3];
    const float* bias = (const float*)d_in[4];
    float* out = (float*)d_out;
    unsigned short* Wf    = (unsigned short*)d_ws;       // 64 KB fragment-ordered W
    unsigned short* sigbf = Wf + 32768;                  // 2 MB bf16 signal

    prep_kernel<<<640, 256, 0, stream>>>(W, sig, Wf, sigbf);
    fused_kernel<<<4096, 512, 0, stream>>>(sigbf, pidx, ck, Wf, bias, out);
}

// Round 19
// 38.732 us; speedup vs baseline: 2.1510x; 2.1510x over previous
//
#include <hip/hip_runtime.h>

// BinaryTreeShConv on MI355X (gfx950).
// out[b,v,i] = relu(bias[i] + sum_{p,c,rn} W[i,c,rn] * K[b,v,p,rn] * sig[b, idx[b,v,p], c])
// B=8 V=4096 P=32 C=32 RN=32 OUT=32, CRN=1024.
//
// R18 = R15 (best, 36.5) with the gather subsystem widened 2B -> 8B:
//  - idx: one coalesced dword load/lane (was 32 s_loads) + 4 __shfl
//  - gathers: 4 x uint2 per lane (8 rows/instr, 8 lanes/row, line-coalesced)
//    written into a patch tile [32p][32c] that ALIASES T_lds (patch fully
//    consumed by phase-A reads before T overwrites it; intra-wave in-order
//    DS + MFMA data dependence guarantee order; phase-B T reads are behind
//    barrier 1). LDS stays 32.9 KB -> 4 blocks/CU (32 waves, 100% cap).
//  - A-fragment read from LDS (16 ds_read_u16, same proven pattern as bfr).
//  - gather VMEM instrs/wave 16 -> 4; gather VALU addressing ~4x down.
// Everything else (ckb staging, phases, 2 barriers, red aliasing, epilogue,
// prep) identical to R15. Numerics identical: absmax 0.25 expected.

typedef __attribute__((ext_vector_type(8))) short bf16x8;
typedef __attribute__((ext_vector_type(4))) short short4v;
typedef __attribute__((ext_vector_type(2))) unsigned int uint2v;
typedef __attribute__((ext_vector_type(16))) float f32x16;
typedef __attribute__((ext_vector_type(4))) float f32x4;

__device__ __forceinline__ unsigned short f2bf_rne(float f) {
    union { float f; unsigned int u; } x;
    x.f = f;
    unsigned int u = x.u;
    return (unsigned short)((u + 0x7fffu + ((u >> 16) & 1u)) >> 16);
}
__device__ __forceinline__ unsigned short f2bf_rh(float f) {  // round-half-up
    union { float f; unsigned int u; } x;
    x.f = f;
    return (unsigned short)((x.u + 0x8000u) >> 16);
}

// Wf[pair=2s+t][lane][j] = bf16(W[i=16t+(lane&15)][crn=32s+8*(lane>>4)+j])
// plus sig f32 -> bf16 (RNE), 8 elements/thread.
__global__ __launch_bounds__(256) void prep_kernel(
        const float* __restrict__ W, const float* __restrict__ sig,
        unsigned short* __restrict__ Wf, unsigned short* __restrict__ sigbf) {
    int tid = blockIdx.x * 256 + threadIdx.x;
    if (tid < 32768) {
        int j = tid & 7;
        int l = (tid >> 3) & 63;
        int pair = tid >> 9;                    // s*2 + t
        int s = pair >> 1;
        int t = pair & 1;
        int i = 16 * t + (l & 15);
        int crn = 32 * s + 8 * (l >> 4) + j;
        Wf[tid] = f2bf_rne(W[i * 1024 + crn]);
    } else {
        int e = (tid - 32768) * 8;              // sig has 1,048,576 elements
        if (e < 8 * 4096 * 32) {
            f32x4 a = *(const f32x4*)(sig + e);
            f32x4 b = *(const f32x4*)(sig + e + 4);
            bf16x8 v;
            v[0] = (short)f2bf_rne(a[0]); v[1] = (short)f2bf_rne(a[1]);
            v[2] = (short)f2bf_rne(a[2]); v[3] = (short)f2bf_rne(a[3]);
            v[4] = (short)f2bf_rne(b[0]); v[5] = (short)f2bf_rne(b[1]);
            v[6] = (short)f2bf_rne(b[2]); v[7] = (short)f2bf_rne(b[3]);
            *(bf16x8*)(sigbf + e) = v;
        }
    }
}

__global__ __launch_bounds__(512, 8) void fused_kernel(
        const unsigned short* __restrict__ sigbf, const int* __restrict__ pidx,
        const float* __restrict__ ck, const unsigned short* __restrict__ Wf,
        const float* __restrict__ bias, float* __restrict__ out) {
    __shared__ __align__(16) unsigned short ckb[8 * 1024];  // ck tiles, then red
    __shared__ __align__(16) unsigned short PT[8 * 1032];   // patch, then T
    const int tid = threadIdx.x;
    const int l = tid & 63;
    const int g = l >> 5;
    const int cc = l & 31;
    const int wu = __builtin_amdgcn_readfirstlane(tid >> 6);  // wave 0..7 (SGPR)
    const int m0 = blockIdx.x * 8;   // 8 bv per block (same b)
    const int b = m0 >> 12;
    const unsigned short* sgb = sigbf + (size_t)b * (4096 * 32);

    // ======== Phase 0: pure streaming; wave wu owns bv wu ========
    // (a) idx: coalesced per-lane dword (lanes 0-31 real, 32-63 duplicates)
    const int idx_vec = pidx[(size_t)(m0 + wu) * 32 + (l & 31)];
    // (b) ck staging for bv wu: 4 f32x4 per lane, issued up front
    f32x4 st[4];
    {
        const f32x4* ckv = (const f32x4*)(ck + (size_t)(m0 + wu) * 1024);
        #pragma unroll
        for (int i = 0; i < 4; ++i) st[i] = ckv[i * 64 + l];
    }
    // (c) patch gathers: 4 x uint2 per lane. Instr i covers rows 8i..8i+7
    //     (8 lanes/row, 8B/lane, line-coalesced); row idx via __shfl.
    //     Patch [32p][32c] bf16 goes into PT[wu] (aliases this wave's T tile).
    unsigned short* pt = PT + wu * 1032;
    {
        const int sub = l >> 3;          // row within group of 8
        const int chunk = (l & 7) * 4;   // ushort offset within 32-ch row
        #pragma unroll
        for (int i = 0; i < 4; ++i) {
            const int row = __shfl(idx_vec, 8 * i + sub, 64);
            const uint2v d = *(const uint2v*)(sgb + (size_t)row * 32 + chunk);
            *(uint2v*)(pt + (8 * i + sub) * 32 + chunk) = d;
        }
    }
    // (d) pack ck -> ckb (own region; intra-wave RAW, no barrier)
    #pragma unroll
    for (int i = 0; i < 4; ++i) {
        union { f32x4 f; unsigned int u[4]; } x;
        x.f = st[i];
        short4v v = { (short)(x.u[0] >> 16), (short)(x.u[1] >> 16),
                      (short)(x.u[2] >> 16), (short)(x.u[3] >> 16) };
        *(short4v*)(ckb + wu * 1024 + (i * 64 + l) * 4) = v;
    }

    // ======== Phase A: stage-A MFMA; wave wu computes T for bv wu ========
    // af from patch (PT[wu]), bfr from ckb[wu] — both own-region LDS reads.
    // T writes overwrite PT[wu] AFTER all patch reads (MFMA data dependence
    // + per-wave in-order DS make this safe without a barrier).
    {
        const unsigned short* ct = ckb + wu * 1024;   // [32p][32rn]
        f32x16 acc = {};
        #pragma unroll
        for (int h = 0; h < 2; ++h) {
            bf16x8 af, bfr;
            #pragma unroll
            for (int j = 0; j < 8; ++j) {
                const int p = h * 16 + 8 * g + j;
                af[j]  = (short)pt[p * 32 + cc];
                bfr[j] = (short)ct[p * 32 + cc];
            }
            acc = __builtin_amdgcn_mfma_f32_32x32x16_bf16(af, bfr, acc, 0, 0, 0);
        }
        // D map (verified): col=cc, row=(r&3)+8*(r>>2)+4*g ; T[c][rn] bf16
        unsigned short* trow = pt + cc + g * 128;
        #pragma unroll
        for (int r = 0; r < 16; ++r)
            trow[((r & 3) + 8 * (r >> 2)) * 32] = f2bf_rh(acc[r]);
    }
    __syncthreads();   // barrier 1: all T tiles ready (patch fully dead)

    // ======== Phase B: k-split s = 4wu..4wu+3, both i-tiles ========
    // A-frag row ln -> T row (ln&7); rows 8-15 broadcast-duplicate 0-7.
    f32x4 acc0 = {}, acc1 = {};
    const int lg = l >> 4;
    const int ln = l & 15;
    #pragma unroll
    for (int si = 0; si < 4; ++si) {
        const int s = 4 * wu + si;
        const bf16x8 af =
            *(const bf16x8*)(PT + (ln & 7) * 1032 + s * 32 + 8 * lg);
        const bf16x8* wrow = (const bf16x8*)(Wf + (size_t)(s * 2) * 512);
        const bf16x8 b0 = wrow[l];        // pair 2s+0, 16B/lane coalesced, L2-hot
        const bf16x8 b1 = wrow[64 + l];   // pair 2s+1
        acc0 = __builtin_amdgcn_mfma_f32_16x16x32_bf16(af, b0, acc0, 0, 0, 0);
        acc1 = __builtin_amdgcn_mfma_f32_16x16x32_bf16(af, b1, acc1, 0, 0, 0);
    }

    // red buffer = ckb (dead after phase A; wave wu overwrites only the
    // region it alone read) — no barrier between T reads and these writes.
    float* red = (float*)ckb;             // 8 waves * 512 f32 = 16,384 B exact
    {
        f32x4* rp = (f32x4*)(red + wu * 512);
        rp[l]      = acc0;                // [w][t=0][l][r]
        rp[64 + l] = acc1;                // [w][t=1][l][r]
    }
    __syncthreads();   // barrier 2: red complete

    // 256 outputs: threads 0-255 -> (bv = tid>>5, i = tid&31); 8-way k-sum.
    if (tid < 256) {
        const int bv  = tid >> 5;
        const int i   = tid & 31;
        const int t   = i >> 4;
        const int col = i & 15;
        const int lgi = bv >> 2;          // 0..1
        const int r   = bv & 3;
        const int li  = lgi * 16 + col;
        const int o   = t * 256 + li * 4 + r;
        float sum = 0.f;
        #pragma unroll
        for (int w2 = 0; w2 < 8; ++w2) sum += red[w2 * 512 + o];
        sum += bias[i];
        out[(size_t)(m0 + bv) * 32 + i] = sum > 0.f ? sum : 0.f;
    }
}

extern "C" void kernel_launch(void* const* d_in, const int* in_sizes, int n_in,
                              void* d_out, int out_size, void* d_ws, size_t ws_size,
                              hipStream_t stream) {
    const float* sig  = (const float*)d_in[0];
    const int*   pidx = (const int*)d_in[1];
    const float* ck   = (const float*)d_in[2];
    const float* W    = (const float*)d_in[3];
    const float* bias = (const float*)d_in[4];
    float* out = (float*)d_out;
    unsigned short* Wf    = (unsigned short*)d_ws;       // 64 KB fragment-ordered W
    unsigned short* sigbf = Wf + 32768;                  // 2 MB bf16 signal

    prep_kernel<<<640, 256, 0, stream>>>(W, sig, Wf, sigbf);
    fused_kernel<<<4096, 512, 0, stream>>>(sigbf, pidx, ck, Wf, bias, out);
}

// Round 20
// 34.890 us; speedup vs baseline: 2.3879x; 1.1101x over previous
//
#include <hip/hip_runtime.h>

// BinaryTreeShConv on MI355X (gfx950).
// out[b,v,i] = relu(bias[i] + sum_{p,c,rn} W[i,c,rn] * K[b,v,p,rn] * sig[b, idx[b,v,p], c])
// B=8 V=4096 P=32 C=32 RN=32 OUT=32, CRN=1024.
//
// R19 = R15 (best, 36.5) + bijective XCD-chunked blockIdx swizzle (T1):
//   swz = (bid & 7) * 512 + (bid >> 3)   [4096 = 8 x 512, bijective]
// XCD x then serves exactly batch x: its L2 keeps ONE 256 KB sigbf slice hot
// (vs all 2 MB under round-robin) against the ck stream's eviction pressure;
// ck reads and out writes become per-XCD contiguous. Everything else is
// byte-identical to R15 (2 barriers, ckb/red aliasing, 512thr/8bv,
// launch_bounds(512,8), prep = Wf pack + sigbf). absmax 0.25 expected.

typedef __attribute__((ext_vector_type(8))) short bf16x8;
typedef __attribute__((ext_vector_type(4))) short short4v;
typedef __attribute__((ext_vector_type(16))) float f32x16;
typedef __attribute__((ext_vector_type(4))) float f32x4;

__device__ __forceinline__ unsigned short f2bf_rne(float f) {
    union { float f; unsigned int u; } x;
    x.f = f;
    unsigned int u = x.u;
    return (unsigned short)((u + 0x7fffu + ((u >> 16) & 1u)) >> 16);
}
__device__ __forceinline__ unsigned short f2bf_rh(float f) {  // round-half-up
    union { float f; unsigned int u; } x;
    x.f = f;
    return (unsigned short)((x.u + 0x8000u) >> 16);
}

// Wf[pair=2s+t][lane][j] = bf16(W[i=16t+(lane&15)][crn=32s+8*(lane>>4)+j])
// plus sig f32 -> bf16 (RNE), 8 elements/thread.
__global__ __launch_bounds__(256) void prep_kernel(
        const float* __restrict__ W, const float* __restrict__ sig,
        unsigned short* __restrict__ Wf, unsigned short* __restrict__ sigbf) {
    int tid = blockIdx.x * 256 + threadIdx.x;
    if (tid < 32768) {
        int j = tid & 7;
        int l = (tid >> 3) & 63;
        int pair = tid >> 9;                    // s*2 + t
        int s = pair >> 1;
        int t = pair & 1;
        int i = 16 * t + (l & 15);
        int crn = 32 * s + 8 * (l >> 4) + j;
        Wf[tid] = f2bf_rne(W[i * 1024 + crn]);
    } else {
        int e = (tid - 32768) * 8;              // sig has 1,048,576 elements
        if (e < 8 * 4096 * 32) {
            f32x4 a = *(const f32x4*)(sig + e);
            f32x4 b = *(const f32x4*)(sig + e + 4);
            bf16x8 v;
            v[0] = (short)f2bf_rne(a[0]); v[1] = (short)f2bf_rne(a[1]);
            v[2] = (short)f2bf_rne(a[2]); v[3] = (short)f2bf_rne(a[3]);
            v[4] = (short)f2bf_rne(b[0]); v[5] = (short)f2bf_rne(b[1]);
            v[6] = (short)f2bf_rne(b[2]); v[7] = (short)f2bf_rne(b[3]);
            *(bf16x8*)(sigbf + e) = v;
        }
    }
}

__global__ __launch_bounds__(512, 8) void fused_kernel(
        const unsigned short* __restrict__ sigbf, const int* __restrict__ pidx,
        const float* __restrict__ ck, const unsigned short* __restrict__ Wf,
        const float* __restrict__ bias, float* __restrict__ out) {
    __shared__ __align__(16) unsigned short ckb[8 * 1024];   // ck tiles, then red
    __shared__ __align__(16) unsigned short T_lds[8 * 1032]; // 16,512 B
    const int tid = threadIdx.x;
    const int l = tid & 63;
    const int g = l >> 5;
    const int cc = l & 31;
    const int wu = __builtin_amdgcn_readfirstlane(tid >> 6);  // wave 0..7 (SGPR)
    // XCD-chunked bijective swizzle: 4096 blocks = 8 XCDs x 512.
    // Physical dispatch slot d -> logical block (d&7)*512 + (d>>3), so each
    // XCD processes one contiguous batch (same b -> one sigbf slice per L2).
    const int bid = blockIdx.x;
    const int swz = (bid & 7) * 512 + (bid >> 3);
    const int m0 = swz * 8;          // 8 bv per block (same b)
    const int b = m0 >> 12;
    const unsigned short* sgb = sigbf + (size_t)b * (4096 * 32);

    // ======== Phase 0: pure streaming; wave wu owns bv wu ========
    // (a) idx: wave-uniform scalar loads (32 ints -> SGPRs)
    int rows[32];
    {
        const int* ip = pidx + (size_t)(m0 + wu) * 32;
        #pragma unroll
        for (int k = 0; k < 32; ++k) rows[k] = ip[k];
    }
    // (b) ck staging for bv wu: 4 KB = 4 f32x4 per lane, issued up front
    f32x4 st[4];
    {
        const f32x4* ckv = (const f32x4*)(ck + (size_t)(m0 + wu) * 1024);
        #pragma unroll
        for (int i = 0; i < 4; ++i) st[i] = ckv[i * 64 + l];
    }
    // (c) gathers: 16 per lane (1 bv), u16 from sigbf; const-indexed rows
    //     + g?hi:lo cndmask (rule #20)
    unsigned short ga[16];
    #pragma unroll
    for (int h = 0; h < 2; ++h) {
        #pragma unroll
        for (int j = 0; j < 8; ++j) {
            const int rlo = rows[h * 16 + j];
            const int rhi = rows[h * 16 + 8 + j];
            const int row = g ? rhi : rlo;
            ga[h * 8 + j] = sgb[row * 32 + cc];
        }
    }
    // (d) pack ck staging to bf16 -> LDS (linear, coalesced b64).
    //     NO barrier: wave wu writes only ckb[wu], and phase A below reads
    //     only ckb[wu] — intra-wave RAW, in-order DS ops + lgkmcnt suffice.
    #pragma unroll
    for (int i = 0; i < 4; ++i) {
        union { f32x4 f; unsigned int u[4]; } x;
        x.f = st[i];
        short4v v = { (short)(x.u[0] >> 16), (short)(x.u[1] >> 16),
                      (short)(x.u[2] >> 16), (short)(x.u[3] >> 16) };
        *(short4v*)(ckb + wu * 1024 + (i * 64 + l) * 4) = v;
    }

    // ======== Phase A: stage-A MFMA; wave wu computes T for bv wu ========
    {
        const unsigned short* ct = ckb + wu * 1024;   // [32p][32rn], own region
        f32x16 acc = {};
        #pragma unroll
        for (int h = 0; h < 2; ++h) {
            bf16x8 af, bfr;
            #pragma unroll
            for (int j = 0; j < 8; ++j) {
                const int p = h * 16 + 8 * g + j;
                af[j]  = (short)ga[h * 8 + j];
                bfr[j] = (short)ct[p * 32 + cc];
            }
            acc = __builtin_amdgcn_mfma_f32_32x32x16_bf16(af, bfr, acc, 0, 0, 0);
        }
        // D map (verified): col=cc, row=(r&3)+8*(r>>2)+4*g ; T[c][rn] bf16
        unsigned short* trow = T_lds + wu * 1032 + cc + g * 128;
        #pragma unroll
        for (int r = 0; r < 16; ++r)
            trow[((r & 3) + 8 * (r >> 2)) * 32] = f2bf_rh(acc[r]);
    }
    __syncthreads();   // barrier 1: all T rows visible to all waves

    // ======== Phase B: k-split s = 4wu..4wu+3, both i-tiles ========
    // A-frag row ln -> T row (ln&7); rows 8-15 broadcast-duplicate 0-7.
    f32x4 acc0 = {}, acc1 = {};
    const int lg = l >> 4;
    const int ln = l & 15;
    #pragma unroll
    for (int si = 0; si < 4; ++si) {
        const int s = 4 * wu + si;
        const bf16x8 af =
            *(const bf16x8*)(T_lds + (ln & 7) * 1032 + s * 32 + 8 * lg);
        const bf16x8* wrow = (const bf16x8*)(Wf + (size_t)(s * 2) * 512);
        const bf16x8 b0 = wrow[l];        // pair 2s+0, 16B/lane coalesced, L2-hot
        const bf16x8 b1 = wrow[64 + l];   // pair 2s+1
        acc0 = __builtin_amdgcn_mfma_f32_16x16x32_bf16(af, b0, acc0, 0, 0, 0);
        acc1 = __builtin_amdgcn_mfma_f32_16x16x32_bf16(af, b1, acc1, 0, 0, 0);
    }

    // red buffer = ckb (dead after phase A; wave wu overwrites only the
    // region it alone read) — no barrier between T reads and these writes.
    float* red = (float*)ckb;             // 8 waves * 512 f32 = 16,384 B exact
    {
        f32x4* rp = (f32x4*)(red + wu * 512);
        rp[l]      = acc0;                // [w][t=0][l][r]
        rp[64 + l] = acc1;                // [w][t=1][l][r]
    }
    __syncthreads();   // barrier 2: red complete

    // 256 outputs: threads 0-255 -> (bv = tid>>5, i = tid&31); 8-way k-sum.
    if (tid < 256) {
        const int bv  = tid >> 5;
        const int i   = tid & 31;
        const int t   = i >> 4;
        const int col = i & 15;
        const int lgi = bv >> 2;          // 0..1
        const int r   = bv & 3;
        const int li  = lgi * 16 + col;
        const int o   = t * 256 + li * 4 + r;
        float sum = 0.f;
        #pragma unroll
        for (int w2 = 0; w2 < 8; ++w2) sum += red[w2 * 512 + o];
        sum += bias[i];
        out[(size_t)(m0 + bv) * 32 + i] = sum > 0.f ? sum : 0.f;
    }
}

extern "C" void kernel_launch(void* const* d_in, const int* in_sizes, int n_in,
                              void* d_out, int out_size, void* d_ws, size_t ws_size,
                              hipStream_t stream) {
    const float* sig  = (const float*)d_in[0];
    const int*   pidx = (const int*)d_in[1];
    const float* ck   = (const float*)d_in[2];
    const float* W    = (const float*)d_in[3];
    const float* bias = (const float*)d_in[4];
    float* out = (float*)d_out;
    unsigned short* Wf    = (unsigned short*)d_ws;       // 64 KB fragment-ordered W
    unsigned short* sigbf = Wf + 32768;                  // 2 MB bf16 signal

    prep_kernel<<<640, 256, 0, stream>>>(W, sig, Wf, sigbf);
    fused_kernel<<<4096, 512, 0, stream>>>(sigbf, pidx, ck, Wf, bias, out);
}